// Round 3
// baseline (49.544 us; speedup 1.0000x reference)
//
#include <hip/hip_runtime.h>
#include <hip/hip_bf16.h>
#include <stdint.h>

typedef __attribute__((ext_vector_type(8))) short short8;   // 8 bf16 MFMA A/B frag
typedef __attribute__((ext_vector_type(4))) float fv4;      // MFMA C/D frag
typedef __attribute__((ext_vector_type(4))) int   iv4;      // 16B pack

constexpr int B_ = 16, A_ = 1024, V_ = 1024, D_ = 512;
constexpr int ROWS_A = B_ * A_;              // 16384
constexpr int ROWS_T = 2 * ROWS_A;           // 32768
constexpr size_t BF_ONE = (size_t)ROWS_A * D_ * 2;          // 16 MiB each
constexpr size_t WS_NEED = 2 * BF_ONE + (size_t)ROWS_T * 4; // 32 MiB + 128 KiB

// fp32 -> bf16 round-to-nearest-even
__device__ __forceinline__ unsigned f2bf(float f) {
    unsigned u = __builtin_bit_cast(unsigned, f);
    return (u + 0x7fffu + ((u >> 16) & 1u)) >> 16;
}

// ---------------- Pass 1: fp32 -> bf16 convert + row squared-norms ----------------
__global__ void __launch_bounds__(256)
convert_kernel(const float* __restrict__ audio, const float* __restrict__ visual,
               ushort* __restrict__ abf, ushort* __restrict__ vbf,
               float* __restrict__ normA, float* __restrict__ normV)
{
    const int lane = threadIdx.x & 63;
    const int wv   = (blockIdx.x * 256 + threadIdx.x) >> 6;
    const int nw   = (gridDim.x * 256) >> 6;

    for (int row = wv; row < ROWS_T; row += nw) {
        const float* src; ushort* dst; float* nd; int r;
        if (row < ROWS_A) { src = audio;  dst = abf; nd = normA; r = row; }
        else              { src = visual; dst = vbf; nd = normV; r = row - ROWS_A; }

        const float* p = src + (size_t)r * D_ + lane * 8;   // one wave = one row
        fv4 x0 = *(const fv4*)p;
        fv4 x1 = *(const fv4*)(p + 4);

        float s = 0.f;
#pragma unroll
        for (int i = 0; i < 4; ++i) s += x0[i] * x0[i] + x1[i] * x1[i];

        iv4 w;
        w[0] = (int)(f2bf(x0[0]) | (f2bf(x0[1]) << 16));
        w[1] = (int)(f2bf(x0[2]) | (f2bf(x0[3]) << 16));
        w[2] = (int)(f2bf(x1[0]) | (f2bf(x1[1]) << 16));
        w[3] = (int)(f2bf(x1[2]) | (f2bf(x1[3]) << 16));
        *(iv4*)(dst + (size_t)r * D_ + lane * 8) = w;

#pragma unroll
        for (int m = 1; m < 64; m <<= 1) s += __shfl_xor(s, m, 64);
        if (lane == 0) nd[r] = s;
    }
}

// ---------------- raw-primitive helpers ----------------
__device__ __forceinline__ void gload16(const void* g, void* l) {
    __builtin_amdgcn_global_load_lds((const __attribute__((address_space(1))) void*)g,
                                     (__attribute__((address_space(3))) void*)l,
                                     16, 0, 0);
}
__device__ __forceinline__ unsigned lds_addr(const void* p) {
    return (unsigned)(unsigned long long)(__attribute__((address_space(3))) const char*)p;
}
__device__ __forceinline__ short8 dsr128(unsigned a) {
    short8 r;
    asm volatile("ds_read_b128 %0, %1" : "=v"(r) : "v"(a));
    return r;
}
#define LGK0() asm volatile("s_waitcnt lgkmcnt(0)")
#define VMC0() asm volatile("s_waitcnt vmcnt(0)")
#define SB0()  __builtin_amdgcn_sched_barrier(0)
#define BAR()  __builtin_amdgcn_s_barrier()

// ---------------- Pass 2: 256x256-tile bf16 GEMM, 2-phase dbuf, fused sqrt ----------------
// 8 waves as 2(M)x4(N); per-wave C = 128x64 = 8x4 frags. BK=64, 8 K-tiles.
// LDS: 2 x (A 256x64 + B 256x64) bf16 = 128 KiB, XOR-chunk swizzled via
// pre-swizzled global source (linear gload_lds dest) + swizzled ds_read.
__global__ void __launch_bounds__(512, 2)
gemm256(const ushort* __restrict__ abf, const ushort* __restrict__ vbf,
        const float* __restrict__ normA, const float* __restrict__ normV,
        float* __restrict__ out)
{
    __shared__ __align__(16) char sA[2][256 * 128];
    __shared__ __align__(16) char sB[2][256 * 128];
    __shared__ float lnrm[512];

    const int t = threadIdx.x, lane = t & 63, w = t >> 6;
    const int wm = w >> 2, wn = w & 3;

    // XCD-bijective swizzle: 256 blocks, each XCD gets 32 = 2 whole batches.
    const int orig = blockIdx.x;
    const int wg   = (orig & 7) * 32 + (orig >> 3);
    const int b = wg >> 4, tile = wg & 15, ab = tile >> 2, vb = tile & 3;

    const ushort* Ag = abf + ((size_t)b * A_ + ab * 256) * D_;
    const ushort* Vg = vbf + ((size_t)b * V_ + vb * 256) * D_;

    // staging: per gload16 issue a wave covers 8 rows x 128B; source pre-swizzled
    const int rl = lane >> 3;            // row-in-group = dest row & 7
    const int cs = (lane & 7) ^ rl;      // swizzled source chunk (involution)
    const ushort* asrc = Ag + (size_t)(w * 8 + rl) * D_ + cs * 8;
    const ushort* vsrc = Vg + (size_t)(w * 8 + rl) * D_ + cs * 8;

    // norms -> LDS (needs real fence+barrier so use __syncthreads once, pre-loop)
    if (t < 256) lnrm[t] = normA[(size_t)b * A_ + ab * 256 + t];
    else         lnrm[t] = normV[(size_t)b * V_ + vb * 256 + (t - 256)];
    __syncthreads();

    fv4 acc[8][4];
#pragma unroll
    for (int m = 0; m < 8; ++m)
#pragma unroll
        for (int n = 0; n < 4; ++n) acc[m][n] = fv4{0.f, 0.f, 0.f, 0.f};

    const int frow = lane & 15, fg = lane >> 4, xk = frow & 7;
    const unsigned sAbase = lds_addr(&sA[0][0]);
    const unsigned sBbase = lds_addr(&sB[0][0]);
    const unsigned arow = (unsigned)((wm * 128 + frow) * 128);
    const unsigned brow = (unsigned)((wn * 64 + frow) * 128);
    const unsigned c0 = (unsigned)(((0 + fg) ^ xk) << 4);   // k=0 chunk (swizzled)
    const unsigned c1 = (unsigned)(((4 + fg) ^ xk) << 4);   // k=1 chunk

    // prologue: stage K-tile 0 into buffer 0, drain own loads
#pragma unroll
    for (int h = 0; h < 4; ++h) {
        gload16(asrc + (size_t)h * 64 * D_, (char*)sA[0] + (h * 64 + w * 8) * 128);
        gload16(vsrc + (size_t)h * 64 * D_, (char*)sB[0] + (h * 64 + w * 8) * 128);
    }
    VMC0();

    short8 av[4][2], bv[4][2];

    for (int kt = 0; kt < 8; ++kt) {
        BAR();                    // tile kt landed workgroup-wide; tile kt-1 reads done
        const int cur = kt & 1;

        if (kt < 7) {             // stage kt+1 into the buffer freed at the barrier
            const size_t soff = (size_t)(kt + 1) * 64;
            char* da = (char*)sA[cur ^ 1] + w * 8 * 128;
            char* db = (char*)sB[cur ^ 1] + w * 8 * 128;
#pragma unroll
            for (int h = 0; h < 4; ++h) {
                gload16(asrc + (size_t)h * 64 * D_ + soff, da + h * 64 * 128);
                gload16(vsrc + (size_t)h * 64 * D_ + soff, db + h * 64 * 128);
            }
        }

        const unsigned Ab = sAbase + (unsigned)cur * 32768u + arow;
        const unsigned Bb = sBbase + (unsigned)cur * 32768u + brow;

        // ---- phase 0: A m0-3 (8 reads) + B n0-1 (4 reads); 16 MFMA ----
#pragma unroll
        for (int m = 0; m < 4; ++m) {
            av[m][0] = dsr128(Ab + m * 2048 + c0);
            av[m][1] = dsr128(Ab + m * 2048 + c1);
        }
#pragma unroll
        for (int n = 0; n < 2; ++n) {
            bv[n][0] = dsr128(Bb + n * 2048 + c0);
            bv[n][1] = dsr128(Bb + n * 2048 + c1);
        }
        LGK0(); SB0();
        __builtin_amdgcn_s_setprio(1);
#pragma unroll
        for (int k = 0; k < 2; ++k)
#pragma unroll
            for (int m = 0; m < 4; ++m)
#pragma unroll
                for (int n = 0; n < 2; ++n)
                    acc[m][n] = __builtin_amdgcn_mfma_f32_16x16x32_bf16(av[m][k], bv[n][k], acc[m][n], 0, 0, 0);
        __builtin_amdgcn_s_setprio(0);

        // ---- phase 1: B n2-3 (4 reads); 16 MFMA (reuse A m0-3) ----
#pragma unroll
        for (int n = 2; n < 4; ++n) {
            bv[n][0] = dsr128(Bb + n * 2048 + c0);
            bv[n][1] = dsr128(Bb + n * 2048 + c1);
        }
        LGK0(); SB0();
        __builtin_amdgcn_s_setprio(1);
#pragma unroll
        for (int k = 0; k < 2; ++k)
#pragma unroll
            for (int m = 0; m < 4; ++m)
#pragma unroll
                for (int n = 2; n < 4; ++n)
                    acc[m][n] = __builtin_amdgcn_mfma_f32_16x16x32_bf16(av[m][k], bv[n][k], acc[m][n], 0, 0, 0);
        __builtin_amdgcn_s_setprio(0);

        // ---- phase 2: A m4-7 (8 reads); 16 MFMA (reuse B n2-3) ----
#pragma unroll
        for (int m = 0; m < 4; ++m) {
            av[m][0] = dsr128(Ab + (m + 4) * 2048 + c0);
            av[m][1] = dsr128(Ab + (m + 4) * 2048 + c1);
        }
        LGK0(); SB0();
        __builtin_amdgcn_s_setprio(1);
#pragma unroll
        for (int k = 0; k < 2; ++k)
#pragma unroll
            for (int m = 0; m < 4; ++m)
#pragma unroll
                for (int n = 2; n < 4; ++n)
                    acc[m + 4][n] = __builtin_amdgcn_mfma_f32_16x16x32_bf16(av[m][k], bv[n][k], acc[m + 4][n], 0, 0, 0);
        __builtin_amdgcn_s_setprio(0);

        // ---- phase 3: no reads; 16 MFMA (reuse A m4-7, B n0-1) ----
        __builtin_amdgcn_s_setprio(1);
#pragma unroll
        for (int k = 0; k < 2; ++k)
#pragma unroll
            for (int m = 0; m < 4; ++m)
#pragma unroll
                for (int n = 0; n < 2; ++n)
                    acc[m + 4][n] = __builtin_amdgcn_mfma_f32_16x16x32_bf16(av[m][k], bv[n][k], acc[m + 4][n], 0, 0, 0);
        __builtin_amdgcn_s_setprio(0);

        VMC0();   // own stage loads for kt+1 landed (after ~4 phases of compute cover)
    }

    // ---- fused epilogue: out = sqrt(max(||a||^2 + ||v||^2 - 2*cross, 0)) ----
    float* Ob = out + (size_t)b * A_ * V_ + (size_t)(ab * 256) * V_ + vb * 256;
#pragma unroll
    for (int m = 0; m < 8; ++m) {
#pragma unroll
        for (int n = 0; n < 4; ++n) {
            const int col = wn * 64 + n * 16 + frow;     // C/D: col = lane&15
            const float vsq = lnrm[256 + col];
#pragma unroll
            for (int j = 0; j < 4; ++j) {
                const int row = wm * 128 + m * 16 + fg * 4 + j;  // row=(lane>>4)*4+reg
                float d2 = lnrm[row] + vsq - 2.f * acc[m][n][j];
                Ob[(size_t)row * V_ + col] = sqrtf(fmaxf(d2, 0.f));
            }
        }
    }
}

// ---------------- Fallback (ws too small): round-1 fused kernel ----------------
__device__ __forceinline__ iv4 pack8(fv4 x, fv4 y) {
    iv4 r;
    r[0] = (int)(f2bf(x[0]) | (f2bf(x[1]) << 16));
    r[1] = (int)(f2bf(x[2]) | (f2bf(x[3]) << 16));
    r[2] = (int)(f2bf(y[0]) | (f2bf(y[1]) << 16));
    r[3] = (int)(f2bf(y[2]) | (f2bf(y[3]) << 16));
    return r;
}
__device__ __forceinline__ int slot_addr(int r, int g) {
    return r * 64 + (((g) ^ ((r >> 1) & 3)) << 4);
}

__global__ void __launch_bounds__(256)
l2dist_fused(const float* __restrict__ audio, const float* __restrict__ visual,
             float* __restrict__ out)
{
    __shared__ __align__(16) char lA[128 * 64];
    __shared__ __align__(16) char lV[128 * 64];
    __shared__ float pA[128][4];
    __shared__ float pV[128][4];
    __shared__ float nA[128];
    __shared__ float nV[128];

    const int t = threadIdx.x, lane = t & 63, wave = t >> 6;
    const int wm = wave >> 1, wn = wave & 1;
    const int vb = blockIdx.x, ab = blockIdx.y, b = blockIdx.z;
    const int r0 = t >> 2, g = t & 3;

    const float* Ap = audio  + ((size_t)b * A_ + (size_t)ab * 128) * D_;
    const float* Vp = visual + ((size_t)b * V_ + (size_t)vb * 128) * D_;

    fv4 acc[4][4];
#pragma unroll
    for (int i = 0; i < 4; ++i)
#pragma unroll
        for (int j = 0; j < 4; ++j) acc[i][j] = fv4{0.f, 0.f, 0.f, 0.f};
    float psA0 = 0.f, psA1 = 0.f, psV0 = 0.f, psV1 = 0.f;
    const int frow = lane & 15, fg = lane >> 4;

    for (int kt = 0; kt < 16; ++kt) {
        const int koff = kt * 32 + g * 8;
        fv4 a0 = *(const fv4*)(Ap + (size_t)r0 * D_ + koff);
        fv4 a1 = *(const fv4*)(Ap + (size_t)r0 * D_ + koff + 4);
        fv4 a2 = *(const fv4*)(Ap + (size_t)(r0 + 64) * D_ + koff);
        fv4 a3 = *(const fv4*)(Ap + (size_t)(r0 + 64) * D_ + koff + 4);
        fv4 v0 = *(const fv4*)(Vp + (size_t)r0 * D_ + koff);
        fv4 v1 = *(const fv4*)(Vp + (size_t)r0 * D_ + koff + 4);
        fv4 v2 = *(const fv4*)(Vp + (size_t)(r0 + 64) * D_ + koff);
        fv4 v3 = *(const fv4*)(Vp + (size_t)(r0 + 64) * D_ + koff + 4);
#pragma unroll
        for (int i = 0; i < 4; ++i) {
            psA0 += a0[i] * a0[i] + a1[i] * a1[i];
            psA1 += a2[i] * a2[i] + a3[i] * a3[i];
            psV0 += v0[i] * v0[i] + v1[i] * v1[i];
            psV1 += v2[i] * v2[i] + v3[i] * v3[i];
        }
        iv4 wa0 = pack8(a0, a1), wa1 = pack8(a2, a3);
        iv4 wv0 = pack8(v0, v1), wv1 = pack8(v2, v3);
        __syncthreads();
        *(iv4*)(lA + slot_addr(r0, g)) = wa0;
        *(iv4*)(lA + slot_addr(r0 + 64, g)) = wa1;
        *(iv4*)(lV + slot_addr(r0, g)) = wv0;
        *(iv4*)(lV + slot_addr(r0 + 64, g)) = wv1;
        __syncthreads();
        short8 af[4], bfr[4];
#pragma unroll
        for (int m = 0; m < 4; ++m)
            af[m] = *(const short8*)(lA + slot_addr(wm * 64 + m * 16 + frow, fg));
#pragma unroll
        for (int n = 0; n < 4; ++n)
            bfr[n] = *(const short8*)(lV + slot_addr(wn * 64 + n * 16 + frow, fg));
#pragma unroll
        for (int m = 0; m < 4; ++m)
#pragma unroll
            for (int n = 0; n < 4; ++n)
                acc[m][n] = __builtin_amdgcn_mfma_f32_16x16x32_bf16(af[m], bfr[n], acc[m][n], 0, 0, 0);
    }

    pA[r0][g] = psA0; pA[r0 + 64][g] = psA1;
    pV[r0][g] = psV0; pV[r0 + 64][g] = psV1;
    __syncthreads();
    if (t < 128) nA[t] = pA[t][0] + pA[t][1] + pA[t][2] + pA[t][3];
    else { int r = t - 128; nV[r] = pV[r][0] + pV[r][1] + pV[r][2] + pV[r][3]; }
    __syncthreads();

    float* Ob = out + (size_t)b * A_ * V_ + ((size_t)ab * 128) * V_ + vb * 128;
#pragma unroll
    for (int m = 0; m < 4; ++m)
#pragma unroll
        for (int n = 0; n < 4; ++n) {
            const int col = wn * 64 + n * 16 + frow;
            const float vsq = nV[col];
#pragma unroll
            for (int j = 0; j < 4; ++j) {
                const int row = wm * 64 + m * 16 + fg * 4 + j;
                float d2 = nA[row] + vsq - 2.f * acc[m][n][j];
                Ob[(size_t)row * V_ + col] = sqrtf(fmaxf(d2, 0.f));
            }
        }
}

extern "C" void kernel_launch(void* const* d_in, const int* in_sizes, int n_in,
                              void* d_out, int out_size, void* d_ws, size_t ws_size,
                              hipStream_t stream) {
    const float* audio  = (const float*)d_in[0];
    const float* visual = (const float*)d_in[1];
    float* out = (float*)d_out;

    if (ws_size >= WS_NEED) {
        char* ws = (char*)d_ws;
        ushort* abf = (ushort*)ws;
        ushort* vbf = (ushort*)(ws + BF_ONE);
        float*  nA  = (float*)(ws + 2 * BF_ONE);
        float*  nV  = nA + ROWS_A;
        convert_kernel<<<2048, 256, 0, stream>>>(audio, visual, abf, vbf, nA, nV);
        gemm256<<<256, 512, 0, stream>>>(abf, vbf, nA, nV, out);
    } else {
        dim3 grid(8, 8, 16);
        l2dist_fused<<<grid, 256, 0, stream>>>(audio, visual, out);
    }
}

// Round 4
// 41.097 us; speedup vs baseline: 1.2055x; 1.2055x over previous
//
#include <hip/hip_runtime.h>
#include <hip/hip_bf16.h>

typedef __attribute__((ext_vector_type(8))) short short8;   // 8 bf16 MFMA A/B frag
typedef __attribute__((ext_vector_type(4))) float fv4;      // MFMA C/D frag

constexpr int B_ = 16, A_ = 1024, V_ = 1024, D_ = 512;

__device__ __forceinline__ unsigned cvtpk(float lo, float hi) {
    unsigned r;
    asm("v_cvt_pk_bf16_f32 %0, %1, %2" : "=v"(r) : "v"(lo), "v"(hi));
    return r;
}
#define SB0() __builtin_amdgcn_sched_barrier(0)

struct Stage { fv4 x0, x1, x2, x3; };

// Fused: fp32 -> bf16 convert + row norms + 256x256 MFMA tile + sqrt epilogue.
// 512 threads = 8 waves (2M x 4N). BK=64, 8 K-tiles, double-buffered LDS.
// One __syncthreads per K-tile (vmcnt drained by consumption before it).
__global__ void __launch_bounds__(512, 2)
l2dist_fused256(const float* __restrict__ audio, const float* __restrict__ visual,
                float* __restrict__ out)
{
    __shared__ __align__(16) char sA[2 * 256 * 128];   // [buf][row 256][64 bf16]
    __shared__ __align__(16) char sB[2 * 256 * 128];
    __shared__ float lnrm[512];                        // [0..255]=A rows, [256..511]=V rows

    const int t = threadIdx.x, lane = t & 63, w = t >> 6;
    const int wm = w >> 2, wn = w & 3;                 // wave C-slab: 128 rows x 64 cols

    // XCD-bijective swizzle: 256 blocks; each XCD gets 32 = 2 whole batches.
    const int orig = blockIdx.x;
    const int wg   = (orig & 7) * 32 + (orig >> 3);
    const int b = wg >> 4, tile = wg & 15, ab = tile >> 2, vb = tile & 3;

    const float* Ag = audio  + ((size_t)b * A_ + ab * 256) * D_;
    const float* Vg = visual + ((size_t)b * V_ + vb * 256) * D_;

    // staging geometry: 4-lane quad per row; thread covers 16 floats of one row
    const int rg  = t >> 2;            // 0..127 row within half-panel
    const int lq  = t & 3;             // quad lane
    const int key = rg & 7;            // swizzle key (same for all quarters)
    const int lqo = ((lq >> 1) << 4) + (lq & 1) * 8;   // byte offset pieces

    const float* g0 = Ag + (size_t)rg * D_ + lq * 4;           // A rows 0-127
    const float* g1 = Ag + (size_t)(128 + rg) * D_ + lq * 4;   // A rows 128-255
    const float* g2 = Vg + (size_t)rg * D_ + lq * 4;           // V rows 0-127
    const float* g3 = Vg + (size_t)(128 + rg) * D_ + lq * 4;   // V rows 128-255

    const int oLo = rg * 128;                // LDS row byte offset, half 0
    const int oHi = (128 + rg) * 128;        // half 1
    float* n0 = &lnrm[rg];
    float* n1 = &lnrm[128 + rg];
    float* n2 = &lnrm[256 + rg];
    float* n3 = &lnrm[384 + rg];

#define ISSUE(S, gbase, koff) do {                                   \
        const float* _p = (gbase) + (koff);                          \
        S.x0 = *(const fv4*)(_p);      S.x1 = *(const fv4*)(_p + 16);\
        S.x2 = *(const fv4*)(_p + 32); S.x3 = *(const fv4*)(_p + 48);\
    } while (0)

    // convert + squared-norm + swizzled LDS write for one quarter (4 chunks)
#define PROC(S, dst, rowoff, nrmp) do {                                          \
        float _s = S.x0[0]*S.x0[0] + S.x0[1]*S.x0[1] + S.x0[2]*S.x0[2] + S.x0[3]*S.x0[3] \
                 + S.x1[0]*S.x1[0] + S.x1[1]*S.x1[1] + S.x1[2]*S.x1[2] + S.x1[3]*S.x1[3] \
                 + S.x2[0]*S.x2[0] + S.x2[1]*S.x2[1] + S.x2[2]*S.x2[2] + S.x2[3]*S.x2[3] \
                 + S.x3[0]*S.x3[0] + S.x3[1]*S.x3[1] + S.x3[2]*S.x3[2] + S.x3[3]*S.x3[3];\
        char* _d = (dst) + (rowoff);                                             \
        { int2 _v; _v.x = (int)cvtpk(S.x0[0], S.x0[1]); _v.y = (int)cvtpk(S.x0[2], S.x0[3]); \
          *(int2*)(_d + ((((0 + (lq >> 1)) ^ key) << 4) + (lq & 1) * 8)) = _v; } \
        { int2 _v; _v.x = (int)cvtpk(S.x1[0], S.x1[1]); _v.y = (int)cvtpk(S.x1[2], S.x1[3]); \
          *(int2*)(_d + ((((2 + (lq >> 1)) ^ key) << 4) + (lq & 1) * 8)) = _v; } \
        { int2 _v; _v.x = (int)cvtpk(S.x2[0], S.x2[1]); _v.y = (int)cvtpk(S.x2[2], S.x2[3]); \
          *(int2*)(_d + ((((4 + (lq >> 1)) ^ key) << 4) + (lq & 1) * 8)) = _v; } \
        { int2 _v; _v.x = (int)cvtpk(S.x3[0], S.x3[1]); _v.y = (int)cvtpk(S.x3[2], S.x3[3]); \
          *(int2*)(_d + ((((6 + (lq >> 1)) ^ key) << 4) + (lq & 1) * 8)) = _v; } \
        _s += __shfl_xor(_s, 1, 64);                                             \
        _s += __shfl_xor(_s, 2, 64);                                             \
        if (lq == 0) *(nrmp) += _s;                                              \
    } while (0)

    // ---- prologue: zero norms, stage tile 0 into buf 0 ----
    lnrm[t] = 0.f;
    __syncthreads();
    {
        Stage q0, q1, q2, q3;
        ISSUE(q0, g0, 0); ISSUE(q1, g1, 0); SB0();
        PROC(q0, sA, oLo, n0);
        ISSUE(q2, g2, 0); SB0();
        PROC(q1, sA, oHi, n1);
        ISSUE(q3, g3, 0); SB0();
        PROC(q2, sB, oLo, n2);
        PROC(q3, sB, oHi, n3);
    }
    __syncthreads();

    fv4 acc[8][4];
#pragma unroll
    for (int m = 0; m < 8; ++m)
#pragma unroll
        for (int n = 0; n < 4; ++n) acc[m][n] = fv4{0.f, 0.f, 0.f, 0.f};

    const int frow = lane & 15, fg = lane >> 4, xk = frow & 7;
    const int cof0 = ((0 + fg) ^ xk) << 4;    // k-half 0 swizzled chunk
    const int cof1 = ((4 + fg) ^ xk) << 4;    // k-half 1

#pragma unroll 1
    for (int kt = 0; kt < 8; ++kt) {
        const int cur = kt & 1;
        char* dstA = sA + (cur ^ 1) * 32768;
        char* dstB = sB + (cur ^ 1) * 32768;
        const char* Ab = sA + cur * 32768 + (wm * 128 + frow) * 128;
        const char* Bb = sB + cur * 32768 + (wn * 64 + frow) * 128;
        const int koff = (kt + 1) * 64;
        const bool st = (kt < 7);

        Stage q0, q1, q2, q3;
        if (st) { ISSUE(q0, g0, koff); ISSUE(q1, g1, koff); SB0(); }

        short8 av[4][2];
        // ---- phase 0: A m0-3, B n0-1; 16 MFMA ----
        {
            short8 bv[2][2];
#pragma unroll
            for (int m = 0; m < 4; ++m) {
                av[m][0] = *(const short8*)(Ab + m * 2048 + cof0);
                av[m][1] = *(const short8*)(Ab + m * 2048 + cof1);
            }
#pragma unroll
            for (int n = 0; n < 2; ++n) {
                bv[n][0] = *(const short8*)(Bb + n * 2048 + cof0);
                bv[n][1] = *(const short8*)(Bb + n * 2048 + cof1);
            }
            __builtin_amdgcn_s_setprio(1);
#pragma unroll
            for (int k = 0; k < 2; ++k)
#pragma unroll
                for (int m = 0; m < 4; ++m)
#pragma unroll
                    for (int n = 0; n < 2; ++n)
                        acc[m][n] = __builtin_amdgcn_mfma_f32_16x16x32_bf16(av[m][k], bv[n][k], acc[m][n], 0, 0, 0);
            __builtin_amdgcn_s_setprio(0);
        }
        if (st) { PROC(q0, dstA, oLo, n0); ISSUE(q2, g2, koff); SB0(); }

        // ---- phase 1: B n2-3; 16 MFMA (reuse av) ----
        short8 bv2[2][2];
        {
#pragma unroll
            for (int n = 0; n < 2; ++n) {
                bv2[n][0] = *(const short8*)(Bb + (n + 2) * 2048 + cof0);
                bv2[n][1] = *(const short8*)(Bb + (n + 2) * 2048 + cof1);
            }
            __builtin_amdgcn_s_setprio(1);
#pragma unroll
            for (int k = 0; k < 2; ++k)
#pragma unroll
                for (int m = 0; m < 4; ++m)
#pragma unroll
                    for (int n = 0; n < 2; ++n)
                        acc[m][n + 2] = __builtin_amdgcn_mfma_f32_16x16x32_bf16(av[m][k], bv2[n][k], acc[m][n + 2], 0, 0, 0);
            __builtin_amdgcn_s_setprio(0);
        }
        if (st) { PROC(q1, dstA, oHi, n1); ISSUE(q3, g3, koff); SB0(); }

        // ---- phase 2: A m4-7; 16 MFMA (reuse bv2) ----
        {
#pragma unroll
            for (int m = 0; m < 4; ++m) {
                av[m][0] = *(const short8*)(Ab + (m + 4) * 2048 + cof0);
                av[m][1] = *(const short8*)(Ab + (m + 4) * 2048 + cof1);
            }
            __builtin_amdgcn_s_setprio(1);
#pragma unroll
            for (int k = 0; k < 2; ++k)
#pragma unroll
                for (int m = 0; m < 4; ++m)
#pragma unroll
                    for (int n = 0; n < 2; ++n)
                        acc[m + 4][n + 2] = __builtin_amdgcn_mfma_f32_16x16x32_bf16(av[m][k], bv2[n][k], acc[m + 4][n + 2], 0, 0, 0);
            __builtin_amdgcn_s_setprio(0);
        }
        if (st) PROC(q2, dstB, oLo, n2);

        // ---- phase 3: B n0-1 re-read; 16 MFMA ----
        {
            short8 bv[2][2];
#pragma unroll
            for (int n = 0; n < 2; ++n) {
                bv[n][0] = *(const short8*)(Bb + n * 2048 + cof0);
                bv[n][1] = *(const short8*)(Bb + n * 2048 + cof1);
            }
            __builtin_amdgcn_s_setprio(1);
#pragma unroll
            for (int k = 0; k < 2; ++k)
#pragma unroll
                for (int m = 0; m < 4; ++m)
#pragma unroll
                    for (int n = 0; n < 2; ++n)
                        acc[m + 4][n] = __builtin_amdgcn_mfma_f32_16x16x32_bf16(av[m][k], bv[n][k], acc[m + 4][n], 0, 0, 0);
            __builtin_amdgcn_s_setprio(0);
        }
        if (st) PROC(q3, dstB, oHi, n3);

        __syncthreads();   // writes to buf^1 committed; reads of buf done
    }

    // ---- fused epilogue: out = sqrt(max(||a||^2 + ||v||^2 - 2*cross, 0)) ----
    float* Ob = out + (size_t)b * A_ * V_ + (size_t)(ab * 256) * V_ + vb * 256;
#pragma unroll
    for (int m = 0; m < 8; ++m) {
#pragma unroll
        for (int n = 0; n < 4; ++n) {
            const int col = wn * 64 + n * 16 + frow;      // C/D: col = lane&15
            const float vsq = lnrm[256 + col];
#pragma unroll
            for (int j = 0; j < 4; ++j) {
                const int row = wm * 128 + m * 16 + fg * 4 + j;   // row=(lane>>4)*4+reg
                float d2 = lnrm[row] + vsq - 2.f * acc[m][n][j];
                Ob[(size_t)row * V_ + col] = sqrtf(fmaxf(d2, 0.f));
            }
        }
    }
#undef ISSUE
#undef PROC
}

extern "C" void kernel_launch(void* const* d_in, const int* in_sizes, int n_in,
                              void* d_out, int out_size, void* d_ws, size_t ws_size,
                              hipStream_t stream) {
    const float* audio  = (const float*)d_in[0];
    const float* visual = (const float*)d_in[1];
    float* out = (float*)d_out;
    l2dist_fused256<<<256, 512, 0, stream>>>(audio, visual, out);
}